// Round 1
// baseline (132.207 us; speedup 1.0000x reference)
//
#include <hip/hip_runtime.h>
#include <stdint.h>

#define NQ 8

// sin/cos of theta (radians) via raw v_sin/v_cos (input in revolutions).
#define INV2PI 0.15915494309189535f
__device__ __forceinline__ float fsinr(float th) { return __builtin_amdgcn_sinf(th * INV2PI); }
__device__ __forceinline__ float fcosr(float th) { return __builtin_amdgcn_cosf(th * INV2PI); }

// ---- cross-lane xor exchange within aligned 32-lane groups ----
// xor1/xor2: DPP quad_perm; xor8: DPP row_ror:8 (within 16-lane rows, ror8 == xor8).
// xor4/xor16: ds_swizzle BitMode (operates within 32-lane groups).
template<int XM>
__device__ __forceinline__ float sx(float v) {
    if constexpr (XM == 0) return v;
    const int x = __float_as_int(v);
    int r;
    if constexpr (XM == 1)      r = __builtin_amdgcn_update_dpp(0, x, 0xB1,  0xF, 0xF, true); // quad [1,0,3,2]
    else if constexpr (XM == 2) r = __builtin_amdgcn_update_dpp(0, x, 0x4E,  0xF, 0xF, true); // quad [2,3,0,1]
    else if constexpr (XM == 8) r = __builtin_amdgcn_update_dpp(0, x, 0x128, 0xF, 0xF, true); // row_ror:8
    else                        r = __builtin_amdgcn_ds_swizzle(x, (XM << 10) | 0x1F);        // 4, 16
    return __int_as_float(r);
}

__device__ __forceinline__ void swapf(float& a, float& b) { float t = a; a = b; b = t; }

// Layout: amp index g = i | (laneq<<3); qubit k -> bit k of g.
// Qubits 0..2 = local bits (i in [0,8)), qubits 3..7 = lane bits (laneq in [0,32)).

// ---- real 2x2 [[a,b],[d,e]] on qubit Q ----
template<int Q>
__device__ __forceinline__ void realGate(float (&sr)[8], float (&si)[8], int laneq,
                                         float a, float b, float d, float e)
{
    if constexpr (Q < 3) {
        constexpr int M = 1 << Q;
#pragma unroll
        for (int i = 0; i < 8; i++) if (!(i & M)) {
            const int j = i | M;
            float x0r = sr[i], x0i = si[i], x1r = sr[j], x1i = si[j];
            sr[i] = a * x0r + b * x1r;  si[i] = a * x0i + b * x1i;
            sr[j] = d * x0r + e * x1r;  si[j] = d * x0i + e * x1i;
        }
    } else {
        constexpr int XM = 1 << (Q - 3);
        const int bit = (laneq >> (Q - 3)) & 1;
        const float sc = bit ? e : a;   // self coefficient
        const float pc = bit ? d : b;   // partner coefficient
#pragma unroll
        for (int i = 0; i < 8; i++) {
            float pr = sx<XM>(sr[i]);
            float pi = sx<XM>(si[i]);
            sr[i] = sc * sr[i] + pc * pr;
            si[i] = sc * si[i] + pc * pi;
        }
    }
}

// ---- RX: [[c, -i s], [-i s, c]] ----
template<int Q>
__device__ __forceinline__ void applyRX(float (&sr)[8], float (&si)[8], int laneq,
                                        float c, float s)
{
    if constexpr (Q < 3) {
        constexpr int M = 1 << Q;
#pragma unroll
        for (int i = 0; i < 8; i++) if (!(i & M)) {
            const int j = i | M;
            float x0r = sr[i], x0i = si[i], x1r = sr[j], x1i = si[j];
            sr[i] = c * x0r + s * x1i;  si[i] = c * x0i - s * x1r;
            sr[j] = c * x1r + s * x0i;  si[j] = c * x1i - s * x0r;
        }
    } else {
        constexpr int XM = 1 << (Q - 3);
#pragma unroll
        for (int i = 0; i < 8; i++) {
            float pr = sx<XM>(sr[i]);
            float pi = sx<XM>(si[i]);
            float nr = c * sr[i] + s * pi;
            float ni = c * si[i] - s * pr;
            sr[i] = nr; si[i] = ni;
        }
    }
}

// ---- RZ: diag(c - i s, c + i s) — shuffle-free ----
template<int Q>
__device__ __forceinline__ void applyRZ(float (&sr)[8], float (&si)[8], int laneq,
                                        float c, float s)
{
    if constexpr (Q >= 3) {
        const int bit = (laneq >> (Q - 3)) & 1;
        const float t = bit ? -s : s;
#pragma unroll
        for (int i = 0; i < 8; i++) {
            float nr = c * sr[i] + t * si[i];
            float ni = c * si[i] - t * sr[i];
            sr[i] = nr; si[i] = ni;
        }
    } else {
#pragma unroll
        for (int i = 0; i < 8; i++) {
            const float t = ((i >> Q) & 1) ? -s : s;
            float nr = c * sr[i] + t * si[i];
            float ni = c * si[i] - t * sr[i];
            sr[i] = nr; si[i] = ni;
        }
    }
}

// ---- Pauli Z ----
template<int Q>
__device__ __forceinline__ void applyZ(float (&sr)[8], float (&si)[8], int laneq)
{
    if constexpr (Q >= 3) {
        const bool f = ((laneq >> (Q - 3)) & 1) != 0;
#pragma unroll
        for (int i = 0; i < 8; i++) {
            sr[i] = f ? -sr[i] : sr[i];
            si[i] = f ? -si[i] : si[i];
        }
    } else {
#pragma unroll
        for (int i = 0; i < 8; i++) if ((i >> Q) & 1) {
            sr[i] = -sr[i]; si[i] = -si[i];
        }
    }
}

// ---- Pauli X ----
template<int Q>
__device__ __forceinline__ void applyX(float (&sr)[8], float (&si)[8], int laneq)
{
    if constexpr (Q < 3) {
        constexpr int M = 1 << Q;
#pragma unroll
        for (int i = 0; i < 8; i++) if (!(i & M)) {
            swapf(sr[i], sr[i | M]); swapf(si[i], si[i | M]);
        }
    } else {
        constexpr int XM = 1 << (Q - 3);
#pragma unroll
        for (int i = 0; i < 8; i++) {
            sr[i] = sx<XM>(sr[i]);
            si[i] = sx<XM>(si[i]);
        }
    }
}

// ---- Pauli Y: [[0,-i],[i,0]] ----
template<int Q>
__device__ __forceinline__ void applyY(float (&sr)[8], float (&si)[8], int laneq)
{
    if constexpr (Q < 3) {
        constexpr int M = 1 << Q;
#pragma unroll
        for (int i = 0; i < 8; i++) if (!(i & M)) {
            const int j = i | M;
            float x0r = sr[i], x0i = si[i], x1r = sr[j], x1i = si[j];
            sr[i] = x1i;  si[i] = -x1r;
            sr[j] = -x0i; si[j] = x0r;
        }
    } else {
        constexpr int XM = 1 << (Q - 3);
        const int bit = (laneq >> (Q - 3)) & 1;
#pragma unroll
        for (int i = 0; i < 8; i++) {
            float pr = sx<XM>(sr[i]);
            float pi = sx<XM>(si[i]);
            sr[i] = bit ? -pi : pi;
            si[i] = bit ? pr : -pr;
        }
    }
}

// ---- CZ(C,T): sign flip when both bits set — shuffle-free ----
template<int C, int T>
__device__ __forceinline__ void applyCZ(float (&sr)[8], float (&si)[8], int laneq)
{
#pragma unroll
    for (int i = 0; i < 8; i++) {
        const int g = i | (laneq << 3);
        const bool f = (((g >> C) & (g >> T)) & 1) != 0;
        sr[i] = f ? -sr[i] : sr[i];
        si[i] = f ? -si[i] : si[i];
    }
}

// ---- controlled bit-flip: new[g] = old[g ^ M] when (g & CM) == CM ----
template<int CM, int M>
__device__ __forceinline__ void applyCPerm(float (&sr)[8], float (&si)[8], int laneq)
{
    constexpr int LX  = M >> 3;    // target in lane bits -> exchange mask
    constexpr int PL  = M & 7;     // target in local bits
    constexpr int CML = CM & 7;    // controls in local bits
    constexpr int CMH = CM >> 3;   // controls in lane bits
    if constexpr (LX != 0) {
#pragma unroll
        for (int i = 0; i < 8; i++) {
            if ((i & CML) == CML) {
                float pr = sx<LX>(sr[i]);
                float pi = sx<LX>(si[i]);
                if constexpr (CMH != 0) {
                    const bool c = (laneq & CMH) == CMH;
                    sr[i] = c ? pr : sr[i];
                    si[i] = c ? pi : si[i];
                } else {
                    sr[i] = pr; si[i] = pi;
                }
            }
        }
    } else {
#pragma unroll
        for (int i = 0; i < 8; i++) {
            if (!(i & PL) && ((i & CML) == CML)) {
                const int j = i | PL;
                if constexpr (CMH != 0) {
                    const bool c = (laneq & CMH) == CMH;
                    float t0r = sr[i], t0i = si[i];
                    sr[i] = c ? sr[j] : sr[i];  si[i] = c ? si[j] : si[i];
                    sr[j] = c ? t0r : sr[j];    si[j] = c ? t0i : si[j];
                } else {
                    swapf(sr[i], sr[j]); swapf(si[i], si[j]);
                }
            }
        }
    }
}

// ---- CSWAP(C; T1,T2): swap bits T1,T2 when control set ----
template<int C, int T1, int T2>
__device__ __forceinline__ void applyCSWAP(float (&sr)[8], float (&si)[8], int laneq)
{
    constexpr int M  = (1 << T1) | (1 << T2);
    constexpr int LX = M >> 3;
    constexpr int PL = M & 7;

    if constexpr (LX == 0) {
        // both targets local: representative i has T1-bit=1, T2-bit=0
#pragma unroll
        for (int i = 0; i < 8; i++) {
            if (((i >> T1) & 1) && !((i >> T2) & 1)) {
                bool skip = false;
                if constexpr (C < 3) { if (!((i >> C) & 1)) skip = true; }
                if (!skip) {
                    const int j = i ^ PL;
                    if constexpr (C >= 3) {
                        const bool c = ((laneq >> (C - 3)) & 1) != 0;
                        float t0r = sr[i], t0i = si[i];
                        sr[i] = c ? sr[j] : sr[i];  si[i] = c ? si[j] : si[i];
                        sr[j] = c ? t0r : sr[j];    si[j] = c ? t0i : si[j];
                    } else {
                        swapf(sr[i], sr[j]); swapf(si[i], si[j]);
                    }
                }
            }
        }
    } else if constexpr (PL == 0) {
        // both targets in lane bits
        bool c = ((((laneq >> (T1 - 3)) ^ (laneq >> (T2 - 3))) & 1) != 0);
        if constexpr (C >= 3) c = c && (((laneq >> (C - 3)) & 1) != 0);
#pragma unroll
        for (int i = 0; i < 8; i++) {
            bool skip = false;
            if constexpr (C < 3) { if (!((i >> C) & 1)) skip = true; }
            if (!skip) {
                float pr = sx<LX>(sr[i]);
                float pi = sx<LX>(si[i]);
                sr[i] = c ? pr : sr[i];
                si[i] = c ? pi : si[i];
            }
        }
    } else {
        // mixed: one local target (PL), one lane target (LX)
        constexpr int TL = (PL == (1 << T1)) ? T2 : T1;    // lane-resident target
        const bool laneT = ((laneq >> (TL - 3)) & 1) != 0;
        bool cc = true;
        if constexpr (C >= 3) cc = ((laneq >> (C - 3)) & 1) != 0;
#pragma unroll
        for (int i = 0; i < 8; i++) {
            if (!(i & PL)) {
                bool skip = false;
                if constexpr (C < 3) { if (!((i >> C) & 1)) skip = true; }
                if (!skip) {
                    const int j = i | PL;
                    // read partner-lane values before any write (lockstep)
                    float a_r = sx<LX>(sr[j]), a_i = sx<LX>(si[j]);  // -> sr[i]
                    float b_r = sx<LX>(sr[i]), b_i = sx<LX>(si[i]);  // -> sr[j]
                    const bool ci = cc && laneT;
                    const bool cj = cc && !laneT;
                    sr[i] = ci ? a_r : sr[i];  si[i] = ci ? a_i : si[i];
                    sr[j] = cj ? b_r : sr[j];  si[j] = cj ? b_i : si[j];
                }
            }
        }
    }
}

// ---- one node step; node N compile-time; design bits passed as packed scalars ----
// dryL: 4 bits (node&3), drotL: 8 bits (2 per node&3), dg2L: 16 bits (4 per node&3)
// RY sincos cached per-thread in cry/sry; trainable-rot sincos held one-angle-per-lane
// in vrc/vrs and fetched with v_readlane (uniform index -> lands in SGPRs).
template<int N>
__device__ __forceinline__ void nodeStep(float (&sr)[8], float (&si)[8], int laneq,
                                         const float (&cry)[8], const float (&sry)[8],
                                         float vrc, float vrs, int layer,
                                         int dryL, int drotL, int dg2L)
{
    constexpr int N1 = (N + 1) & 7;
    constexpr int N2 = (N + 2) & 7;
    constexpr int SL = N & 3;

    const bool ryOn = ((dryL >> SL) & 1) != 0;
    const int rot = (drotL >> (2 * SL)) & 3;

    if (rot < 3) {
        const int rIdx = layer * NQ + N;   // uniform (SGPR) lane index
        const float cb = __int_as_float(__builtin_amdgcn_readlane(__float_as_int(vrc), rIdx));
        const float sb = __int_as_float(__builtin_amdgcn_readlane(__float_as_int(vrs), rIdx));
        if (ryOn && rot == 1) {
            // RY(a) then RY(b) == RY(a+b): angle-sum on uniform scalars, one gate apply
            const float c = cb * cry[N] - sb * sry[N];
            const float s = sb * cry[N] + cb * sry[N];
            realGate<N>(sr, si, laneq, c, -s, s, c);
        } else {
            if (ryOn) realGate<N>(sr, si, laneq, cry[N], -sry[N], sry[N], cry[N]);
            if (rot == 0)      applyRX<N>(sr, si, laneq, cb, sb);
            else if (rot == 1) realGate<N>(sr, si, laneq, cb, -sb, sb, cb);
            else               applyRZ<N>(sr, si, laneq, cb, sb);
        }
    } else if (ryOn) {
        realGate<N>(sr, si, laneq, cry[N], -sry[N], sry[N], cry[N]);
    }

    // 3) entangling / extra gate
    const int g2 = (dg2L >> (4 * SL)) & 15;
    switch (g2) {
        case 1: {
            const float r = 0.70710678118654752f;
            realGate<N>(sr, si, laneq, r, r, r, -r);
        } break;
        case 2: applyX<N>(sr, si, laneq); break;
        case 3: applyY<N>(sr, si, laneq); break;
        case 4: applyZ<N>(sr, si, laneq); break;
        case 5: applyCPerm<(1 << N), (1 << N1)>(sr, si, laneq); break;
        case 6: applyCSWAP<N, N1, N2>(sr, si, laneq); break;
        case 7: applyCPerm<(1 << N) | (1 << N1), (1 << N2)>(sr, si, laneq); break;
        case 8: applyCZ<N, N1>(sr, si, laneq); break;
        default: break;
    }
}

__global__ __launch_bounds__(256, 4) void qsim_kernel(
    const float* __restrict__ feats,    // [B, 8]
    const float* __restrict__ qp,       // [48]
    const int* __restrict__ dry,        // [24]
    const int* __restrict__ drot,       // [24]
    const int* __restrict__ dg2,        // [24]
    float* __restrict__ out,            // [B, 8]
    int B)
{
    __shared__ float lds_fv[8][8];      // [group][angle], 256 B

    const int tid   = threadIdx.x;
    const int laneq = tid & 31;                               // lane within element group
    const int grp   = tid >> 5;                               // group within block (0..7)
    const int b     = blockIdx.x * 8 + grp;                   // batch element

    // stage this element's 8 RY angles into LDS (written and read within one wave)
    if (laneq < 8)
        lds_fv[grp][laneq] = feats[(size_t)b * NQ + laneq];

    // ---- trainable-rot sincos: lane k of each wave computes angle k (2 trans/thread
    //      instead of 2 per gate); fetched later via v_readlane ----
    const int wl = tid & 63;
    const int ai = (wl < 48) ? wl : 0;
    const float ra = qp[ai] * 0.5f;
    const float vrc = fcosr(ra);
    const float vrs = fsinr(ra);

    // ---- pack the (uniform) design into SGPRs via readfirstlane ----
    uint32_t dryP = 0;
    uint64_t drotP = 0;
    uint32_t g2P0 = 0, g2P1 = 0, g2P2 = 0;
#pragma unroll
    for (int k = 0; k < 24; k++) {
        dryP  |= (uint32_t)(__builtin_amdgcn_readfirstlane(dry[k]) & 1) << k;
        drotP |= (uint64_t)(__builtin_amdgcn_readfirstlane(drot[k]) & 3) << (2 * k);
    }
#pragma unroll
    for (int k = 0; k < 8; k++) {
        g2P0 |= (uint32_t)(__builtin_amdgcn_readfirstlane(dg2[k])      & 15) << (4 * k);
        g2P1 |= (uint32_t)(__builtin_amdgcn_readfirstlane(dg2[8 + k])  & 15) << (4 * k);
        g2P2 |= (uint32_t)(__builtin_amdgcn_readfirstlane(dg2[16 + k]) & 15) << (4 * k);
    }

    // ---- per-element RY sincos cache: computed ONCE (angles identical every layer) ----
    float cry[8], sry[8];
#pragma unroll
    for (int n = 0; n < 8; n++) {
        const float th = lds_fv[grp][n] * 0.5f;
        cry[n] = fcosr(th);
        sry[n] = fsinr(th);
    }

    // H^8 |0> = uniform amplitude 1/16
    float sr[8], si[8];
#pragma unroll
    for (int i = 0; i < 8; i++) { sr[i] = 0.0625f; si[i] = 0.0f; }

#pragma unroll 1
    for (int layer = 0; layer < 6; layer++) {
        // per-layer design slice (scalar shifts, no memory)
        const int dryL  = (int)((dryP >> (layer * 4)) & 0xF);
        const int drotL = (int)((drotP >> (layer * 8)) & 0xFF);
        const uint32_t g2w = (layer >= 4) ? g2P2 : ((layer >= 2) ? g2P1 : g2P0);
        const int dg2L  = (int)((g2w >> ((layer & 1) * 16)) & 0xFFFF);

        nodeStep<0>(sr, si, laneq, cry, sry, vrc, vrs, layer, dryL, drotL, dg2L);
        nodeStep<1>(sr, si, laneq, cry, sry, vrc, vrs, layer, dryL, drotL, dg2L);
        nodeStep<2>(sr, si, laneq, cry, sry, vrc, vrs, layer, dryL, drotL, dg2L);
        nodeStep<3>(sr, si, laneq, cry, sry, vrc, vrs, layer, dryL, drotL, dg2L);
        nodeStep<4>(sr, si, laneq, cry, sry, vrc, vrs, layer, dryL, drotL, dg2L);
        nodeStep<5>(sr, si, laneq, cry, sry, vrc, vrs, layer, dryL, drotL, dg2L);
        nodeStep<6>(sr, si, laneq, cry, sry, vrc, vrs, layer, dryL, drotL, dg2L);
        nodeStep<7>(sr, si, laneq, cry, sry, vrc, vrs, layer, dryL, drotL, dg2L);
    }

    // ---- epilogue: <Z_q> ----
    float tot = 0.f, s0 = 0.f, s1 = 0.f, s2 = 0.f;
#pragma unroll
    for (int i = 0; i < 8; i++) {
        float p = sr[i] * sr[i] + si[i] * si[i];
        tot += p;
        if (!(i & 1)) s0 += p;
        if (!(i & 2)) s1 += p;
        if (!(i & 4)) s2 += p;
    }
    float e[3] = { 2.f * s0 - tot, 2.f * s1 - tot, 2.f * s2 - tot };

    // sum e[0..2] over the 32-lane group
#pragma unroll
    for (int q = 0; q < 3; q++) {
        e[q] += sx<1>(e[q]);
        e[q] += sx<2>(e[q]);
        e[q] += sx<4>(e[q]);
        e[q] += sx<8>(e[q]);
        e[q] += sx<16>(e[q]);
    }
    // FWHT on tot: after 5 stages, laneq = (1<<k) holds <Z_{3+k}>
    { float pv = sx<1>(tot);  tot = (laneq & 1)  ? (pv - tot) : (pv + tot); }
    { float pv = sx<2>(tot);  tot = (laneq & 2)  ? (pv - tot) : (pv + tot); }
    { float pv = sx<4>(tot);  tot = (laneq & 4)  ? (pv - tot) : (pv + tot); }
    { float pv = sx<8>(tot);  tot = (laneq & 8)  ? (pv - tot) : (pv + tot); }
    { float pv = sx<16>(tot); tot = (laneq & 16) ? (pv - tot) : (pv + tot); }

    float* ob = out + (size_t)b * NQ;
    if (laneq == 0) { ob[0] = e[0]; ob[1] = e[1]; ob[2] = e[2]; }
    if (laneq && !(laneq & (laneq - 1)))          // laneq in {1,2,4,8,16}
        ob[3 + __builtin_ctz(laneq)] = tot;
}

extern "C" void kernel_launch(void* const* d_in, const int* in_sizes, int n_in,
                              void* d_out, int out_size, void* d_ws, size_t ws_size,
                              hipStream_t stream)
{
    (void)n_in; (void)out_size; (void)d_ws; (void)ws_size;
    const float* feats   = (const float*)d_in[0];
    const float* qparams = (const float*)d_in[1];
    const int* dry       = (const int*)d_in[2];
    const int* drot      = (const int*)d_in[3];
    const int* dg2       = (const int*)d_in[4];
    float* out           = (float*)d_out;

    const int B = in_sizes[0] / NQ;             // 16384
    const int blocks = (B + 7) / 8;             // 8 elements per 256-thread block
    qsim_kernel<<<blocks, 256, 0, stream>>>(feats, qparams, dry, drot, dg2, out, B);
}

// Round 2
// 115.565 us; speedup vs baseline: 1.1440x; 1.1440x over previous
//
#include <hip/hip_runtime.h>
#include <stdint.h>

#define NQ 8

// v_sin/v_cos take input in REVOLUTIONS. Fold the /2 (half-angle) and 1/2pi
// into one multiplier applied to the raw angle.
#define HALF_INV2PI 0.07957747154594767f   // 0.5 * 1/(2*pi)

// ---- cross-lane xor exchange within aligned 32-lane groups ----
// xor1/xor2: DPP quad_perm; xor8: DPP row_ror:8 (within 16-lane rows, ror8 == xor8).
// xor4/xor16: ds_swizzle BitMode (operates within 32-lane groups).
template<int XM>
__device__ __forceinline__ float sx(float v) {
    if constexpr (XM == 0) return v;
    const int x = __float_as_int(v);
    int r;
    if constexpr (XM == 1)      r = __builtin_amdgcn_update_dpp(0, x, 0xB1,  0xF, 0xF, true); // quad [1,0,3,2]
    else if constexpr (XM == 2) r = __builtin_amdgcn_update_dpp(0, x, 0x4E,  0xF, 0xF, true); // quad [2,3,0,1]
    else if constexpr (XM == 8) r = __builtin_amdgcn_update_dpp(0, x, 0x128, 0xF, 0xF, true); // row_ror:8
    else                        r = __builtin_amdgcn_ds_swizzle(x, (XM << 10) | 0x1F);        // 4, 16
    return __int_as_float(r);
}

__device__ __forceinline__ void swapf(float& a, float& b) { float t = a; a = b; b = t; }

// Layout: amp index g = i | (laneq<<3); qubit k -> bit k of g.
// Qubits 0..2 = local bits (i in [0,8)), qubits 3..7 = lane bits (laneq in [0,32)).

// ---- real 2x2 [[a,b],[d,e]] on qubit Q ----
template<int Q>
__device__ __forceinline__ void realGate(float (&sr)[8], float (&si)[8], int laneq,
                                         float a, float b, float d, float e)
{
    if constexpr (Q < 3) {
        constexpr int M = 1 << Q;
#pragma unroll
        for (int i = 0; i < 8; i++) if (!(i & M)) {
            const int j = i | M;
            float x0r = sr[i], x0i = si[i], x1r = sr[j], x1i = si[j];
            sr[i] = a * x0r + b * x1r;  si[i] = a * x0i + b * x1i;
            sr[j] = d * x0r + e * x1r;  si[j] = d * x0i + e * x1i;
        }
    } else {
        constexpr int XM = 1 << (Q - 3);
        const int bit = (laneq >> (Q - 3)) & 1;
        const float sc = bit ? e : a;   // self coefficient
        const float pc = bit ? d : b;   // partner coefficient
#pragma unroll
        for (int i = 0; i < 8; i++) {
            float pr = sx<XM>(sr[i]);
            float pi = sx<XM>(si[i]);
            sr[i] = sc * sr[i] + pc * pr;
            si[i] = sc * si[i] + pc * pi;
        }
    }
}

// ---- RX: [[c, -i s], [-i s, c]] ----
template<int Q>
__device__ __forceinline__ void applyRX(float (&sr)[8], float (&si)[8], int laneq,
                                        float c, float s)
{
    if constexpr (Q < 3) {
        constexpr int M = 1 << Q;
#pragma unroll
        for (int i = 0; i < 8; i++) if (!(i & M)) {
            const int j = i | M;
            float x0r = sr[i], x0i = si[i], x1r = sr[j], x1i = si[j];
            sr[i] = c * x0r + s * x1i;  si[i] = c * x0i - s * x1r;
            sr[j] = c * x1r + s * x0i;  si[j] = c * x1i - s * x0r;
        }
    } else {
        constexpr int XM = 1 << (Q - 3);
#pragma unroll
        for (int i = 0; i < 8; i++) {
            float pr = sx<XM>(sr[i]);
            float pi = sx<XM>(si[i]);
            float nr = c * sr[i] + s * pi;
            float ni = c * si[i] - s * pr;
            sr[i] = nr; si[i] = ni;
        }
    }
}

// ---- RZ: diag(c - i s, c + i s) — shuffle-free ----
template<int Q>
__device__ __forceinline__ void applyRZ(float (&sr)[8], float (&si)[8], int laneq,
                                        float c, float s)
{
    if constexpr (Q >= 3) {
        const int bit = (laneq >> (Q - 3)) & 1;
        const float t = bit ? -s : s;
#pragma unroll
        for (int i = 0; i < 8; i++) {
            float nr = c * sr[i] + t * si[i];
            float ni = c * si[i] - t * sr[i];
            sr[i] = nr; si[i] = ni;
        }
    } else {
#pragma unroll
        for (int i = 0; i < 8; i++) {
            const float t = ((i >> Q) & 1) ? -s : s;
            float nr = c * sr[i] + t * si[i];
            float ni = c * si[i] - t * sr[i];
            sr[i] = nr; si[i] = ni;
        }
    }
}

// ---- Pauli Z ----
template<int Q>
__device__ __forceinline__ void applyZ(float (&sr)[8], float (&si)[8], int laneq)
{
    if constexpr (Q >= 3) {
        const bool f = ((laneq >> (Q - 3)) & 1) != 0;
#pragma unroll
        for (int i = 0; i < 8; i++) {
            sr[i] = f ? -sr[i] : sr[i];
            si[i] = f ? -si[i] : si[i];
        }
    } else {
#pragma unroll
        for (int i = 0; i < 8; i++) if ((i >> Q) & 1) {
            sr[i] = -sr[i]; si[i] = -si[i];
        }
    }
}

// ---- Pauli X ----
template<int Q>
__device__ __forceinline__ void applyX(float (&sr)[8], float (&si)[8], int laneq)
{
    if constexpr (Q < 3) {
        constexpr int M = 1 << Q;
#pragma unroll
        for (int i = 0; i < 8; i++) if (!(i & M)) {
            swapf(sr[i], sr[i | M]); swapf(si[i], si[i | M]);
        }
    } else {
        constexpr int XM = 1 << (Q - 3);
#pragma unroll
        for (int i = 0; i < 8; i++) {
            sr[i] = sx<XM>(sr[i]);
            si[i] = sx<XM>(si[i]);
        }
    }
}

// ---- Pauli Y: [[0,-i],[i,0]] ----
template<int Q>
__device__ __forceinline__ void applyY(float (&sr)[8], float (&si)[8], int laneq)
{
    if constexpr (Q < 3) {
        constexpr int M = 1 << Q;
#pragma unroll
        for (int i = 0; i < 8; i++) if (!(i & M)) {
            const int j = i | M;
            float x0r = sr[i], x0i = si[i], x1r = sr[j], x1i = si[j];
            sr[i] = x1i;  si[i] = -x1r;
            sr[j] = -x0i; si[j] = x0r;
        }
    } else {
        constexpr int XM = 1 << (Q - 3);
        const int bit = (laneq >> (Q - 3)) & 1;
#pragma unroll
        for (int i = 0; i < 8; i++) {
            float pr = sx<XM>(sr[i]);
            float pi = sx<XM>(si[i]);
            sr[i] = bit ? -pi : pi;
            si[i] = bit ? pr : -pr;
        }
    }
}

// ---- CZ(C,T): sign flip when both bits set — shuffle-free ----
template<int C, int T>
__device__ __forceinline__ void applyCZ(float (&sr)[8], float (&si)[8], int laneq)
{
#pragma unroll
    for (int i = 0; i < 8; i++) {
        const int g = i | (laneq << 3);
        const bool f = (((g >> C) & (g >> T)) & 1) != 0;
        sr[i] = f ? -sr[i] : sr[i];
        si[i] = f ? -si[i] : si[i];
    }
}

// ---- controlled bit-flip: new[g] = old[g ^ M] when (g & CM) == CM ----
template<int CM, int M>
__device__ __forceinline__ void applyCPerm(float (&sr)[8], float (&si)[8], int laneq)
{
    constexpr int LX  = M >> 3;    // target in lane bits -> exchange mask
    constexpr int PL  = M & 7;     // target in local bits
    constexpr int CML = CM & 7;    // controls in local bits
    constexpr int CMH = CM >> 3;   // controls in lane bits
    if constexpr (LX != 0) {
#pragma unroll
        for (int i = 0; i < 8; i++) {
            if ((i & CML) == CML) {
                float pr = sx<LX>(sr[i]);
                float pi = sx<LX>(si[i]);
                if constexpr (CMH != 0) {
                    const bool c = (laneq & CMH) == CMH;
                    sr[i] = c ? pr : sr[i];
                    si[i] = c ? pi : si[i];
                } else {
                    sr[i] = pr; si[i] = pi;
                }
            }
        }
    } else {
#pragma unroll
        for (int i = 0; i < 8; i++) {
            if (!(i & PL) && ((i & CML) == CML)) {
                const int j = i | PL;
                if constexpr (CMH != 0) {
                    const bool c = (laneq & CMH) == CMH;
                    float t0r = sr[i], t0i = si[i];
                    sr[i] = c ? sr[j] : sr[i];  si[i] = c ? si[j] : si[i];
                    sr[j] = c ? t0r : sr[j];    si[j] = c ? t0i : si[j];
                } else {
                    swapf(sr[i], sr[j]); swapf(si[i], si[j]);
                }
            }
        }
    }
}

// ---- CSWAP(C; T1,T2): swap bits T1,T2 when control set ----
template<int C, int T1, int T2>
__device__ __forceinline__ void applyCSWAP(float (&sr)[8], float (&si)[8], int laneq)
{
    constexpr int M  = (1 << T1) | (1 << T2);
    constexpr int LX = M >> 3;
    constexpr int PL = M & 7;

    if constexpr (LX == 0) {
        // both targets local: representative i has T1-bit=1, T2-bit=0
#pragma unroll
        for (int i = 0; i < 8; i++) {
            if (((i >> T1) & 1) && !((i >> T2) & 1)) {
                bool skip = false;
                if constexpr (C < 3) { if (!((i >> C) & 1)) skip = true; }
                if (!skip) {
                    const int j = i ^ PL;
                    if constexpr (C >= 3) {
                        const bool c = ((laneq >> (C - 3)) & 1) != 0;
                        float t0r = sr[i], t0i = si[i];
                        sr[i] = c ? sr[j] : sr[i];  si[i] = c ? si[j] : si[i];
                        sr[j] = c ? t0r : sr[j];    si[j] = c ? t0i : si[j];
                    } else {
                        swapf(sr[i], sr[j]); swapf(si[i], si[j]);
                    }
                }
            }
        }
    } else if constexpr (PL == 0) {
        // both targets in lane bits
        bool c = ((((laneq >> (T1 - 3)) ^ (laneq >> (T2 - 3))) & 1) != 0);
        if constexpr (C >= 3) c = c && (((laneq >> (C - 3)) & 1) != 0);
#pragma unroll
        for (int i = 0; i < 8; i++) {
            bool skip = false;
            if constexpr (C < 3) { if (!((i >> C) & 1)) skip = true; }
            if (!skip) {
                float pr = sx<LX>(sr[i]);
                float pi = sx<LX>(si[i]);
                sr[i] = c ? pr : sr[i];
                si[i] = c ? pi : si[i];
            }
        }
    } else {
        // mixed: one local target (PL), one lane target (LX)
        constexpr int TL = (PL == (1 << T1)) ? T2 : T1;    // lane-resident target
        const bool laneT = ((laneq >> (TL - 3)) & 1) != 0;
        bool cc = true;
        if constexpr (C >= 3) cc = ((laneq >> (C - 3)) & 1) != 0;
#pragma unroll
        for (int i = 0; i < 8; i++) {
            if (!(i & PL)) {
                bool skip = false;
                if constexpr (C < 3) { if (!((i >> C) & 1)) skip = true; }
                if (!skip) {
                    const int j = i | PL;
                    // read partner-lane values before any write (lockstep)
                    float a_r = sx<LX>(sr[j]), a_i = sx<LX>(si[j]);  // -> sr[i]
                    float b_r = sx<LX>(sr[i]), b_i = sx<LX>(si[i]);  // -> sr[j]
                    const bool ci = cc && laneT;
                    const bool cj = cc && !laneT;
                    sr[i] = ci ? a_r : sr[i];  si[i] = ci ? a_i : si[i];
                    sr[j] = cj ? b_r : sr[j];  si[j] = cj ? b_i : si[j];
                }
            }
        }
    }
}

// ---- one node step; node N compile-time; design bits passed as packed scalars ----
// dryL: 4 bits (node&3), drotL: 8 bits (2 per node&3), dg2L: 16 bits (4 per node&3)
// All sincos values come from LDS (computed once in the prologue):
//   ryCS[n]  = (cos(feat_n/2), sin(feat_n/2))   per batch element (broadcast in group)
//   rotCS[k] = (cos(qp_k/2),  sin(qp_k/2))      block-uniform broadcast
template<int N>
__device__ __forceinline__ void nodeStep(float (&sr)[8], float (&si)[8], int laneq,
                                         const float2* ryCS, const float2* rotCS,
                                         int layer, int dryL, int drotL, int dg2L)
{
    constexpr int N1 = (N + 1) & 7;
    constexpr int N2 = (N + 2) & 7;
    constexpr int SL = N & 3;

    const bool ryOn = ((dryL >> SL) & 1) != 0;
    const int rot = (drotL >> (2 * SL)) & 3;

    if (rot < 3) {
        const float2 t = rotCS[layer * NQ + N];     // ds_read_b64, uniform addr
        const float cb = t.x, sb = t.y;
        if (ryOn && rot == 1) {
            // RY(a) then RY(b) == RY(a+b): angle-sum on the cached pairs
            const float2 a = ryCS[N];
            const float c = cb * a.x - sb * a.y;
            const float s = sb * a.x + cb * a.y;
            realGate<N>(sr, si, laneq, c, -s, s, c);
        } else {
            if (ryOn) {
                const float2 a = ryCS[N];
                realGate<N>(sr, si, laneq, a.x, -a.y, a.y, a.x);
            }
            if (rot == 0)      applyRX<N>(sr, si, laneq, cb, sb);
            else if (rot == 1) realGate<N>(sr, si, laneq, cb, -sb, sb, cb);
            else               applyRZ<N>(sr, si, laneq, cb, sb);
        }
    } else if (ryOn) {
        const float2 a = ryCS[N];
        realGate<N>(sr, si, laneq, a.x, -a.y, a.y, a.x);
    }

    // 3) entangling / extra gate
    const int g2 = (dg2L >> (4 * SL)) & 15;
    switch (g2) {
        case 1: {
            const float r = 0.70710678118654752f;
            realGate<N>(sr, si, laneq, r, r, r, -r);
        } break;
        case 2: applyX<N>(sr, si, laneq); break;
        case 3: applyY<N>(sr, si, laneq); break;
        case 4: applyZ<N>(sr, si, laneq); break;
        case 5: applyCPerm<(1 << N), (1 << N1)>(sr, si, laneq); break;
        case 6: applyCSWAP<N, N1, N2>(sr, si, laneq); break;
        case 7: applyCPerm<(1 << N) | (1 << N1), (1 << N2)>(sr, si, laneq); break;
        case 8: applyCZ<N, N1>(sr, si, laneq); break;
        default: break;
    }
}

__global__ __launch_bounds__(256, 4) void qsim_kernel(
    const float* __restrict__ feats,    // [B, 8]
    const float* __restrict__ qp,       // [48]
    const int* __restrict__ dry,        // [24]
    const int* __restrict__ drot,       // [24]
    const int* __restrict__ dg2,        // [24]
    float* __restrict__ out,            // [B, 8]
    int B)
{
    __shared__ float2 lds_ry[8][8];     // per-group (c,s) of RY angles, 512 B
    __shared__ float2 lds_rot[48];      // block-uniform (c,s) of trainable angles, 384 B

    const int tid   = threadIdx.x;
    const int laneq = tid & 31;                               // lane within element group
    const int grp   = tid >> 5;                               // group within block (0..7)
    const int b     = blockIdx.x * 8 + grp;                   // batch element

    // ---- prologue: sincos caches (each value computed exactly once per block) ----
    if (tid < 48) {
        const float th = qp[tid] * HALF_INV2PI;               // revolutions of theta/2
        lds_rot[tid] = make_float2(__builtin_amdgcn_cosf(th), __builtin_amdgcn_sinf(th));
    }
    if (laneq < 8) {
        const float th = feats[(size_t)b * NQ + laneq] * HALF_INV2PI;
        lds_ry[grp][laneq] = make_float2(__builtin_amdgcn_cosf(th), __builtin_amdgcn_sinf(th));
    }

    // ---- pack the (uniform) design into SGPRs via readfirstlane ----
    uint32_t dryP = 0;
    uint64_t drotP = 0;
    uint32_t g2P0 = 0, g2P1 = 0, g2P2 = 0;
#pragma unroll
    for (int k = 0; k < 24; k++) {
        dryP  |= (uint32_t)(__builtin_amdgcn_readfirstlane(dry[k]) & 1) << k;
        drotP |= (uint64_t)(__builtin_amdgcn_readfirstlane(drot[k]) & 3) << (2 * k);
    }
#pragma unroll
    for (int k = 0; k < 8; k++) {
        g2P0 |= (uint32_t)(__builtin_amdgcn_readfirstlane(dg2[k])      & 15) << (4 * k);
        g2P1 |= (uint32_t)(__builtin_amdgcn_readfirstlane(dg2[8 + k])  & 15) << (4 * k);
        g2P2 |= (uint32_t)(__builtin_amdgcn_readfirstlane(dg2[16 + k]) & 15) << (4 * k);
    }

    __syncthreads();                    // lds_rot written by wave 0, read by all waves

    const float2* ryCS  = &lds_ry[grp][0];
    const float2* rotCS = &lds_rot[0];

    // H^8 |0> = uniform amplitude 1/16
    float sr[8], si[8];
#pragma unroll
    for (int i = 0; i < 8; i++) { sr[i] = 0.0625f; si[i] = 0.0f; }

#pragma unroll 1
    for (int layer = 0; layer < 6; layer++) {
        // per-layer design slice (scalar shifts, no memory)
        const int dryL  = (int)((dryP >> (layer * 4)) & 0xF);
        const int drotL = (int)((drotP >> (layer * 8)) & 0xFF);
        const uint32_t g2w = (layer >= 4) ? g2P2 : ((layer >= 2) ? g2P1 : g2P0);
        const int dg2L  = (int)((g2w >> ((layer & 1) * 16)) & 0xFFFF);

        nodeStep<0>(sr, si, laneq, ryCS, rotCS, layer, dryL, drotL, dg2L);
        nodeStep<1>(sr, si, laneq, ryCS, rotCS, layer, dryL, drotL, dg2L);
        nodeStep<2>(sr, si, laneq, ryCS, rotCS, layer, dryL, drotL, dg2L);
        nodeStep<3>(sr, si, laneq, ryCS, rotCS, layer, dryL, drotL, dg2L);
        nodeStep<4>(sr, si, laneq, ryCS, rotCS, layer, dryL, drotL, dg2L);
        nodeStep<5>(sr, si, laneq, ryCS, rotCS, layer, dryL, drotL, dg2L);
        nodeStep<6>(sr, si, laneq, ryCS, rotCS, layer, dryL, drotL, dg2L);
        nodeStep<7>(sr, si, laneq, ryCS, rotCS, layer, dryL, drotL, dg2L);
    }

    // ---- epilogue: <Z_q> ----
    float tot = 0.f, s0 = 0.f, s1 = 0.f, s2 = 0.f;
#pragma unroll
    for (int i = 0; i < 8; i++) {
        float p = sr[i] * sr[i] + si[i] * si[i];
        tot += p;
        if (!(i & 1)) s0 += p;
        if (!(i & 2)) s1 += p;
        if (!(i & 4)) s2 += p;
    }
    float e[3] = { 2.f * s0 - tot, 2.f * s1 - tot, 2.f * s2 - tot };

    // sum e[0..2] over the 32-lane group
#pragma unroll
    for (int q = 0; q < 3; q++) {
        e[q] += sx<1>(e[q]);
        e[q] += sx<2>(e[q]);
        e[q] += sx<4>(e[q]);
        e[q] += sx<8>(e[q]);
        e[q] += sx<16>(e[q]);
    }
    // FWHT on tot: after 5 stages, laneq = (1<<k) holds <Z_{3+k}>
    { float pv = sx<1>(tot);  tot = (laneq & 1)  ? (pv - tot) : (pv + tot); }
    { float pv = sx<2>(tot);  tot = (laneq & 2)  ? (pv - tot) : (pv + tot); }
    { float pv = sx<4>(tot);  tot = (laneq & 4)  ? (pv - tot) : (pv + tot); }
    { float pv = sx<8>(tot);  tot = (laneq & 8)  ? (pv - tot) : (pv + tot); }
    { float pv = sx<16>(tot); tot = (laneq & 16) ? (pv - tot) : (pv + tot); }

    float* ob = out + (size_t)b * NQ;
    if (laneq == 0) { ob[0] = e[0]; ob[1] = e[1]; ob[2] = e[2]; }
    if (laneq && !(laneq & (laneq - 1)))          // laneq in {1,2,4,8,16}
        ob[3 + __builtin_ctz(laneq)] = tot;
}

extern "C" void kernel_launch(void* const* d_in, const int* in_sizes, int n_in,
                              void* d_out, int out_size, void* d_ws, size_t ws_size,
                              hipStream_t stream)
{
    (void)n_in; (void)out_size; (void)d_ws; (void)ws_size;
    const float* feats   = (const float*)d_in[0];
    const float* qparams = (const float*)d_in[1];
    const int* dry       = (const int*)d_in[2];
    const int* drot      = (const int*)d_in[3];
    const int* dg2       = (const int*)d_in[4];
    float* out           = (float*)d_out;

    const int B = in_sizes[0] / NQ;             // 16384
    const int blocks = (B + 7) / 8;             // 8 elements per 256-thread block
    qsim_kernel<<<blocks, 256, 0, stream>>>(feats, qparams, dry, drot, dg2, out, B);
}

// Round 3
// 113.643 us; speedup vs baseline: 1.1633x; 1.0169x over previous
//
#include <hip/hip_runtime.h>
#include <stdint.h>

#define NQ 8

// v_sin/v_cos take input in REVOLUTIONS. Fold the /2 (half-angle) and 1/2pi
// into one multiplier applied to the raw angle.
#define HALF_INV2PI 0.07957747154594767f   // 0.5 * 1/(2*pi)

// ---- packed 2xf32 (full-rate on CDNA2+): amplitude = (re, im) in a VGPR pair ----
typedef float f32x2 __attribute__((ext_vector_type(2)));

__device__ __forceinline__ f32x2 pk2(float x, float y) { f32x2 r; r.x = x; r.y = y; return r; }
__device__ __forceinline__ f32x2 pkb(float x)          { f32x2 r; r.x = x; r.y = x; return r; }

// d = a*b + c on both halves, one VALU instruction each (VOP3P).
__device__ __forceinline__ f32x2 pk_fma(f32x2 a, f32x2 b, f32x2 c) {
    f32x2 d;
    asm("v_pk_fma_f32 %0, %1, %2, %3" : "=v"(d) : "v"(a), "v"(b), "v"(c));
    return d;
}
__device__ __forceinline__ f32x2 pk_mul(f32x2 a, f32x2 b) {
    f32x2 d;
    asm("v_pk_mul_f32 %0, %1, %2" : "=v"(d) : "v"(a), "v"(b));
    return d;
}

// ---- cross-lane xor exchange within aligned 32-lane groups ----
// xor1/xor2: DPP quad_perm; xor8: DPP row_ror:8 (within 16-lane rows, ror8 == xor8).
// xor4/xor16: ds_swizzle BitMode (operates within 32-lane groups).
template<int XM>
__device__ __forceinline__ float sx(float v) {
    if constexpr (XM == 0) return v;
    const int x = __float_as_int(v);
    int r;
    if constexpr (XM == 1)      r = __builtin_amdgcn_update_dpp(0, x, 0xB1,  0xF, 0xF, true); // quad [1,0,3,2]
    else if constexpr (XM == 2) r = __builtin_amdgcn_update_dpp(0, x, 0x4E,  0xF, 0xF, true); // quad [2,3,0,1]
    else if constexpr (XM == 8) r = __builtin_amdgcn_update_dpp(0, x, 0x128, 0xF, 0xF, true); // row_ror:8
    else                        r = __builtin_amdgcn_ds_swizzle(x, (XM << 10) | 0x1F);        // 4, 16
    return __int_as_float(r);
}

// full (re,im) partner fetch: two 32-bit exchanges
template<int XM>
__device__ __forceinline__ f32x2 sxp(f32x2 v) {
    f32x2 r; r.x = sx<XM>(v.x); r.y = sx<XM>(v.y); return r;
}
// partner fetched with components SWAPPED: returns (partner.im, partner.re)
template<int XM>
__device__ __forceinline__ f32x2 sxp_swap(f32x2 v) {
    f32x2 r; r.x = sx<XM>(v.y); r.y = sx<XM>(v.x); return r;
}

__device__ __forceinline__ void swapv(f32x2& a, f32x2& b) { f32x2 t = a; a = b; b = t; }

// Layout: amp index g = i | (laneq<<3); qubit k -> bit k of g.
// Qubits 0..2 = local bits (i in [0,8)), qubits 3..7 = lane bits (laneq in [0,32)).

// ---- real 2x2 [[a,b],[d,e]] on qubit Q — packed: same real coef on re and im ----
template<int Q>
__device__ __forceinline__ void realGate(f32x2 (&v)[8], int laneq,
                                         float a, float b, float d, float e)
{
    if constexpr (Q < 3) {
        constexpr int M = 1 << Q;
        const f32x2 a2 = pkb(a), b2 = pkb(b), d2 = pkb(d), e2 = pkb(e);
#pragma unroll
        for (int i = 0; i < 8; i++) if (!(i & M)) {
            const int j = i | M;
            const f32x2 x0 = v[i], x1 = v[j];
            v[i] = pk_fma(a2, x0, pk_mul(b2, x1));
            v[j] = pk_fma(d2, x0, pk_mul(e2, x1));
        }
    } else {
        constexpr int XM = 1 << (Q - 3);
        const int bit = (laneq >> (Q - 3)) & 1;
        const f32x2 sc2 = pkb(bit ? e : a);   // self coefficient
        const f32x2 pc2 = pkb(bit ? d : b);   // partner coefficient
#pragma unroll
        for (int i = 0; i < 8; i++) {
            const f32x2 p = sxp<XM>(v[i]);
            v[i] = pk_fma(sc2, v[i], pk_mul(pc2, p));
        }
    }
}

// ---- RX: [[c, -i s], [-i s, c]] ----
// new.re = c*re + s*partner.im ; new.im = c*im - s*partner.re
template<int Q>
__device__ __forceinline__ void applyRX(f32x2 (&v)[8], int laneq, float c, float s)
{
    if constexpr (Q < 3) {
        constexpr int M = 1 << Q;
#pragma unroll
        for (int i = 0; i < 8; i++) if (!(i & M)) {
            const int j = i | M;
            const f32x2 x0 = v[i], x1 = v[j];
            v[i] = pk2(c * x0.x + s * x1.y, c * x0.y - s * x1.x);
            v[j] = pk2(c * x1.x + s * x0.y, c * x1.y - s * x0.x);
        }
    } else {
        constexpr int XM = 1 << (Q - 3);
        const f32x2 c2  = pkb(c);
        const f32x2 sn2 = pk2(s, -s);
#pragma unroll
        for (int i = 0; i < 8; i++) {
            const f32x2 ps = sxp_swap<XM>(v[i]);   // (partner.im, partner.re)
            v[i] = pk_fma(c2, v[i], pk_mul(sn2, ps));
        }
    }
}

// ---- RZ: diag(c - i s, c + i s) — shuffle-free, scalar (cross-component) ----
template<int Q>
__device__ __forceinline__ void applyRZ(f32x2 (&v)[8], int laneq, float c, float s)
{
    if constexpr (Q >= 3) {
        const int bit = (laneq >> (Q - 3)) & 1;
        const float t = bit ? -s : s;
#pragma unroll
        for (int i = 0; i < 8; i++) {
            const float nr = c * v[i].x + t * v[i].y;
            const float ni = c * v[i].y - t * v[i].x;
            v[i] = pk2(nr, ni);
        }
    } else {
#pragma unroll
        for (int i = 0; i < 8; i++) {
            const float t = ((i >> Q) & 1) ? -s : s;
            const float nr = c * v[i].x + t * v[i].y;
            const float ni = c * v[i].y - t * v[i].x;
            v[i] = pk2(nr, ni);
        }
    }
}

// ---- Pauli Z ----
template<int Q>
__device__ __forceinline__ void applyZ(f32x2 (&v)[8], int laneq)
{
    if constexpr (Q >= 3) {
        const bool f = ((laneq >> (Q - 3)) & 1) != 0;
#pragma unroll
        for (int i = 0; i < 8; i++) {
            v[i].x = f ? -v[i].x : v[i].x;
            v[i].y = f ? -v[i].y : v[i].y;
        }
    } else {
#pragma unroll
        for (int i = 0; i < 8; i++) if ((i >> Q) & 1) {
            v[i].x = -v[i].x; v[i].y = -v[i].y;
        }
    }
}

// ---- Pauli X ----
template<int Q>
__device__ __forceinline__ void applyX(f32x2 (&v)[8], int laneq)
{
    if constexpr (Q < 3) {
        constexpr int M = 1 << Q;
#pragma unroll
        for (int i = 0; i < 8; i++) if (!(i & M)) {
            swapv(v[i], v[i | M]);
        }
    } else {
        constexpr int XM = 1 << (Q - 3);
#pragma unroll
        for (int i = 0; i < 8; i++) {
            v[i] = sxp<XM>(v[i]);
        }
    }
}

// ---- Pauli Y: [[0,-i],[i,0]] ----
template<int Q>
__device__ __forceinline__ void applyY(f32x2 (&v)[8], int laneq)
{
    if constexpr (Q < 3) {
        constexpr int M = 1 << Q;
#pragma unroll
        for (int i = 0; i < 8; i++) if (!(i & M)) {
            const int j = i | M;
            const f32x2 x0 = v[i], x1 = v[j];
            v[i] = pk2(x1.y, -x1.x);
            v[j] = pk2(-x0.y, x0.x);
        }
    } else {
        constexpr int XM = 1 << (Q - 3);
        const int bit = (laneq >> (Q - 3)) & 1;
#pragma unroll
        for (int i = 0; i < 8; i++) {
            const f32x2 p = sxp<XM>(v[i]);
            v[i].x = bit ? -p.y : p.y;
            v[i].y = bit ? p.x : -p.x;
        }
    }
}

// ---- CZ(C,T): sign flip when both bits set — shuffle-free ----
template<int C, int T>
__device__ __forceinline__ void applyCZ(f32x2 (&v)[8], int laneq)
{
#pragma unroll
    for (int i = 0; i < 8; i++) {
        const int g = i | (laneq << 3);
        const bool f = (((g >> C) & (g >> T)) & 1) != 0;
        v[i].x = f ? -v[i].x : v[i].x;
        v[i].y = f ? -v[i].y : v[i].y;
    }
}

// ---- controlled bit-flip: new[g] = old[g ^ M] when (g & CM) == CM ----
template<int CM, int M>
__device__ __forceinline__ void applyCPerm(f32x2 (&v)[8], int laneq)
{
    constexpr int LX  = M >> 3;    // target in lane bits -> exchange mask
    constexpr int PL  = M & 7;     // target in local bits
    constexpr int CML = CM & 7;    // controls in local bits
    constexpr int CMH = CM >> 3;   // controls in lane bits
    if constexpr (LX != 0) {
#pragma unroll
        for (int i = 0; i < 8; i++) {
            if ((i & CML) == CML) {
                const f32x2 p = sxp<LX>(v[i]);
                if constexpr (CMH != 0) {
                    const bool c = (laneq & CMH) == CMH;
                    v[i].x = c ? p.x : v[i].x;
                    v[i].y = c ? p.y : v[i].y;
                } else {
                    v[i] = p;
                }
            }
        }
    } else {
#pragma unroll
        for (int i = 0; i < 8; i++) {
            if (!(i & PL) && ((i & CML) == CML)) {
                const int j = i | PL;
                if constexpr (CMH != 0) {
                    const bool c = (laneq & CMH) == CMH;
                    const f32x2 t0 = v[i];
                    v[i].x = c ? v[j].x : v[i].x;  v[i].y = c ? v[j].y : v[i].y;
                    v[j].x = c ? t0.x : v[j].x;    v[j].y = c ? t0.y : v[j].y;
                } else {
                    swapv(v[i], v[j]);
                }
            }
        }
    }
}

// ---- CSWAP(C; T1,T2): swap bits T1,T2 when control set ----
template<int C, int T1, int T2>
__device__ __forceinline__ void applyCSWAP(f32x2 (&v)[8], int laneq)
{
    constexpr int M  = (1 << T1) | (1 << T2);
    constexpr int LX = M >> 3;
    constexpr int PL = M & 7;

    if constexpr (LX == 0) {
        // both targets local: representative i has T1-bit=1, T2-bit=0
#pragma unroll
        for (int i = 0; i < 8; i++) {
            if (((i >> T1) & 1) && !((i >> T2) & 1)) {
                bool skip = false;
                if constexpr (C < 3) { if (!((i >> C) & 1)) skip = true; }
                if (!skip) {
                    const int j = i ^ PL;
                    if constexpr (C >= 3) {
                        const bool c = ((laneq >> (C - 3)) & 1) != 0;
                        const f32x2 t0 = v[i];
                        v[i].x = c ? v[j].x : v[i].x;  v[i].y = c ? v[j].y : v[i].y;
                        v[j].x = c ? t0.x : v[j].x;    v[j].y = c ? t0.y : v[j].y;
                    } else {
                        swapv(v[i], v[j]);
                    }
                }
            }
        }
    } else if constexpr (PL == 0) {
        // both targets in lane bits
        bool c = ((((laneq >> (T1 - 3)) ^ (laneq >> (T2 - 3))) & 1) != 0);
        if constexpr (C >= 3) c = c && (((laneq >> (C - 3)) & 1) != 0);
#pragma unroll
        for (int i = 0; i < 8; i++) {
            bool skip = false;
            if constexpr (C < 3) { if (!((i >> C) & 1)) skip = true; }
            if (!skip) {
                const f32x2 p = sxp<LX>(v[i]);
                v[i].x = c ? p.x : v[i].x;
                v[i].y = c ? p.y : v[i].y;
            }
        }
    } else {
        // mixed: one local target (PL), one lane target (LX)
        constexpr int TL = (PL == (1 << T1)) ? T2 : T1;    // lane-resident target
        const bool laneT = ((laneq >> (TL - 3)) & 1) != 0;
        bool cc = true;
        if constexpr (C >= 3) cc = ((laneq >> (C - 3)) & 1) != 0;
#pragma unroll
        for (int i = 0; i < 8; i++) {
            if (!(i & PL)) {
                bool skip = false;
                if constexpr (C < 3) { if (!((i >> C) & 1)) skip = true; }
                if (!skip) {
                    const int j = i | PL;
                    // read partner-lane values before any write (lockstep)
                    const f32x2 a = sxp<LX>(v[j]);  // -> v[i]
                    const f32x2 b = sxp<LX>(v[i]);  // -> v[j]
                    const bool ci = cc && laneT;
                    const bool cj = cc && !laneT;
                    v[i].x = ci ? a.x : v[i].x;  v[i].y = ci ? a.y : v[i].y;
                    v[j].x = cj ? b.x : v[j].x;  v[j].y = cj ? b.y : v[j].y;
                }
            }
        }
    }
}

// ---- one node step; node N compile-time; design bits passed as packed scalars ----
// dryL: 4 bits (node&3), drotL: 8 bits (2 per node&3), dg2L: 16 bits (4 per node&3)
// All sincos values come from LDS (computed once in the prologue):
//   ryCS[n]  = (cos(feat_n/2), sin(feat_n/2))   per batch element (broadcast in group)
//   rotCS[k] = (cos(qp_k/2),  sin(qp_k/2))      block-uniform broadcast
template<int N>
__device__ __forceinline__ void nodeStep(f32x2 (&v)[8], int laneq,
                                         const float2* ryCS, const float2* rotCS,
                                         int layer, int dryL, int drotL, int dg2L)
{
    constexpr int N1 = (N + 1) & 7;
    constexpr int N2 = (N + 2) & 7;
    constexpr int SL = N & 3;

    const bool ryOn = ((dryL >> SL) & 1) != 0;
    const int rot = (drotL >> (2 * SL)) & 3;

    if (rot < 3) {
        const float2 t = rotCS[layer * NQ + N];     // ds_read_b64, uniform addr
        const float cb = t.x, sb = t.y;
        if (ryOn && rot == 1) {
            // RY(a) then RY(b) == RY(a+b): angle-sum on the cached pairs
            const float2 a = ryCS[N];
            const float c = cb * a.x - sb * a.y;
            const float s = sb * a.x + cb * a.y;
            realGate<N>(v, laneq, c, -s, s, c);
        } else {
            if (ryOn) {
                const float2 a = ryCS[N];
                realGate<N>(v, laneq, a.x, -a.y, a.y, a.x);
            }
            if (rot == 0)      applyRX<N>(v, laneq, cb, sb);
            else if (rot == 1) realGate<N>(v, laneq, cb, -sb, sb, cb);
            else               applyRZ<N>(v, laneq, cb, sb);
        }
    } else if (ryOn) {
        const float2 a = ryCS[N];
        realGate<N>(v, laneq, a.x, -a.y, a.y, a.x);
    }

    // 3) entangling / extra gate
    const int g2 = (dg2L >> (4 * SL)) & 15;
    switch (g2) {
        case 1: {
            const float r = 0.70710678118654752f;
            realGate<N>(v, laneq, r, r, r, -r);
        } break;
        case 2: applyX<N>(v, laneq); break;
        case 3: applyY<N>(v, laneq); break;
        case 4: applyZ<N>(v, laneq); break;
        case 5: applyCPerm<(1 << N), (1 << N1)>(v, laneq); break;
        case 6: applyCSWAP<N, N1, N2>(v, laneq); break;
        case 7: applyCPerm<(1 << N) | (1 << N1), (1 << N2)>(v, laneq); break;
        case 8: applyCZ<N, N1>(v, laneq); break;
        default: break;
    }
}

__global__ __launch_bounds__(256, 4) void qsim_kernel(
    const float* __restrict__ feats,    // [B, 8]
    const float* __restrict__ qp,       // [48]
    const int* __restrict__ dry,        // [24]
    const int* __restrict__ drot,       // [24]
    const int* __restrict__ dg2,        // [24]
    float* __restrict__ out,            // [B, 8]
    int B)
{
    __shared__ float2 lds_ry[8][8];     // per-group (c,s) of RY angles, 512 B
    __shared__ float2 lds_rot[48];      // block-uniform (c,s) of trainable angles, 384 B

    const int tid   = threadIdx.x;
    const int laneq = tid & 31;                               // lane within element group
    const int grp   = tid >> 5;                               // group within block (0..7)
    const int b     = blockIdx.x * 8 + grp;                   // batch element

    // ---- prologue: sincos caches (each value computed exactly once per block) ----
    if (tid < 48) {
        const float th = qp[tid] * HALF_INV2PI;               // revolutions of theta/2
        lds_rot[tid] = make_float2(__builtin_amdgcn_cosf(th), __builtin_amdgcn_sinf(th));
    }
    if (laneq < 8) {
        const float th = feats[(size_t)b * NQ + laneq] * HALF_INV2PI;
        lds_ry[grp][laneq] = make_float2(__builtin_amdgcn_cosf(th), __builtin_amdgcn_sinf(th));
    }

    // ---- pack the (uniform) design into SGPRs via readfirstlane ----
    uint32_t dryP = 0;
    uint64_t drotP = 0;
    uint32_t g2P0 = 0, g2P1 = 0, g2P2 = 0;
#pragma unroll
    for (int k = 0; k < 24; k++) {
        dryP  |= (uint32_t)(__builtin_amdgcn_readfirstlane(dry[k]) & 1) << k;
        drotP |= (uint64_t)(__builtin_amdgcn_readfirstlane(drot[k]) & 3) << (2 * k);
    }
#pragma unroll
    for (int k = 0; k < 8; k++) {
        g2P0 |= (uint32_t)(__builtin_amdgcn_readfirstlane(dg2[k])      & 15) << (4 * k);
        g2P1 |= (uint32_t)(__builtin_amdgcn_readfirstlane(dg2[8 + k])  & 15) << (4 * k);
        g2P2 |= (uint32_t)(__builtin_amdgcn_readfirstlane(dg2[16 + k]) & 15) << (4 * k);
    }

    __syncthreads();                    // lds_rot written by wave 0, read by all waves

    const float2* ryCS  = &lds_ry[grp][0];
    const float2* rotCS = &lds_rot[0];

    // H^8 |0> = uniform amplitude 1/16
    f32x2 v[8];
#pragma unroll
    for (int i = 0; i < 8; i++) { v[i] = pk2(0.0625f, 0.0f); }

#pragma unroll 1
    for (int layer = 0; layer < 6; layer++) {
        // per-layer design slice (scalar shifts, no memory)
        const int dryL  = (int)((dryP >> (layer * 4)) & 0xF);
        const int drotL = (int)((drotP >> (layer * 8)) & 0xFF);
        const uint32_t g2w = (layer >= 4) ? g2P2 : ((layer >= 2) ? g2P1 : g2P0);
        const int dg2L  = (int)((g2w >> ((layer & 1) * 16)) & 0xFFFF);

        nodeStep<0>(v, laneq, ryCS, rotCS, layer, dryL, drotL, dg2L);
        nodeStep<1>(v, laneq, ryCS, rotCS, layer, dryL, drotL, dg2L);
        nodeStep<2>(v, laneq, ryCS, rotCS, layer, dryL, drotL, dg2L);
        nodeStep<3>(v, laneq, ryCS, rotCS, layer, dryL, drotL, dg2L);
        nodeStep<4>(v, laneq, ryCS, rotCS, layer, dryL, drotL, dg2L);
        nodeStep<5>(v, laneq, ryCS, rotCS, layer, dryL, drotL, dg2L);
        nodeStep<6>(v, laneq, ryCS, rotCS, layer, dryL, drotL, dg2L);
        nodeStep<7>(v, laneq, ryCS, rotCS, layer, dryL, drotL, dg2L);
    }

    // ---- epilogue: <Z_q> ----
    float tot = 0.f, s0 = 0.f, s1 = 0.f, s2 = 0.f;
#pragma unroll
    for (int i = 0; i < 8; i++) {
        const float p = v[i].x * v[i].x + v[i].y * v[i].y;
        tot += p;
        if (!(i & 1)) s0 += p;
        if (!(i & 2)) s1 += p;
        if (!(i & 4)) s2 += p;
    }
    float e[3] = { 2.f * s0 - tot, 2.f * s1 - tot, 2.f * s2 - tot };

    // sum e[0..2] over the 32-lane group
#pragma unroll
    for (int q = 0; q < 3; q++) {
        e[q] += sx<1>(e[q]);
        e[q] += sx<2>(e[q]);
        e[q] += sx<4>(e[q]);
        e[q] += sx<8>(e[q]);
        e[q] += sx<16>(e[q]);
    }
    // FWHT on tot: after 5 stages, laneq = (1<<k) holds <Z_{3+k}>
    { float pv = sx<1>(tot);  tot = (laneq & 1)  ? (pv - tot) : (pv + tot); }
    { float pv = sx<2>(tot);  tot = (laneq & 2)  ? (pv - tot) : (pv + tot); }
    { float pv = sx<4>(tot);  tot = (laneq & 4)  ? (pv - tot) : (pv + tot); }
    { float pv = sx<8>(tot);  tot = (laneq & 8)  ? (pv - tot) : (pv + tot); }
    { float pv = sx<16>(tot); tot = (laneq & 16) ? (pv - tot) : (pv + tot); }

    float* ob = out + (size_t)b * NQ;
    if (laneq == 0) { ob[0] = e[0]; ob[1] = e[1]; ob[2] = e[2]; }
    if (laneq && !(laneq & (laneq - 1)))          // laneq in {1,2,4,8,16}
        ob[3 + __builtin_ctz(laneq)] = tot;
}

extern "C" void kernel_launch(void* const* d_in, const int* in_sizes, int n_in,
                              void* d_out, int out_size, void* d_ws, size_t ws_size,
                              hipStream_t stream)
{
    (void)n_in; (void)out_size; (void)d_ws; (void)ws_size;
    const float* feats   = (const float*)d_in[0];
    const float* qparams = (const float*)d_in[1];
    const int* dry       = (const int*)d_in[2];
    const int* drot      = (const int*)d_in[3];
    const int* dg2       = (const int*)d_in[4];
    float* out           = (float*)d_out;

    const int B = in_sizes[0] / NQ;             // 16384
    const int blocks = (B + 7) / 8;             // 8 elements per 256-thread block
    qsim_kernel<<<blocks, 256, 0, stream>>>(feats, qparams, dry, drot, dg2, out, B);
}

// Round 4
// 107.186 us; speedup vs baseline: 1.2334x; 1.0602x over previous
//
#include <hip/hip_runtime.h>
#include <stdint.h>

#define NQ 8

// v_sin/v_cos take input in REVOLUTIONS. Fold the /2 (half-angle) and 1/2pi
// into one multiplier applied to the raw angle.
#define HALF_INV2PI 0.07957747154594767f   // 0.5 * 1/(2*pi)

// ---- packed 2xf32 (full-rate on CDNA2+): amplitude = (re, im) in a VGPR pair ----
typedef float f32x2 __attribute__((ext_vector_type(2)));

__device__ __forceinline__ f32x2 pk2(float x, float y) { f32x2 r; r.x = x; r.y = y; return r; }
__device__ __forceinline__ f32x2 pkb(float x)          { f32x2 r; r.x = x; r.y = x; return r; }

// d = a*b + c on both halves, one VALU instruction each (VOP3P).
__device__ __forceinline__ f32x2 pk_fma(f32x2 a, f32x2 b, f32x2 c) {
    f32x2 d;
    asm("v_pk_fma_f32 %0, %1, %2, %3" : "=v"(d) : "v"(a), "v"(b), "v"(c));
    return d;
}
__device__ __forceinline__ f32x2 pk_mul(f32x2 a, f32x2 b) {
    f32x2 d;
    asm("v_pk_mul_f32 %0, %1, %2" : "=v"(d) : "v"(a), "v"(b));
    return d;
}
// Cross-component variants via VOP3P op_sel/neg modifiers (packed-f32 op_sel
// selects which 32-bit register of the 64-bit source feeds each result half):
// d.lo = a.hi*b.lo + c.lo ; d.hi = a.lo*(-b.hi) + c.hi    [swap a; negate b's hi term]
__device__ __forceinline__ f32x2 pk_fma_sa_nh(f32x2 a, f32x2 b, f32x2 c) {
    f32x2 d;
    asm("v_pk_fma_f32 %0, %1, %2, %3 op_sel:[1,0,0] op_sel_hi:[0,1,1] neg_hi:[0,1,0]"
        : "=v"(d) : "v"(a), "v"(b), "v"(c));
    return d;
}
// d.lo = a.hi*(-b.lo) + c.lo ; d.hi = a.lo*b.hi + c.hi    [swap a; negate b's lo term]
__device__ __forceinline__ f32x2 pk_fma_sa_nl(f32x2 a, f32x2 b, f32x2 c) {
    f32x2 d;
    asm("v_pk_fma_f32 %0, %1, %2, %3 op_sel:[1,0,0] op_sel_hi:[0,1,1] neg_lo:[0,1,0]"
        : "=v"(d) : "v"(a), "v"(b), "v"(c));
    return d;
}
// d.lo = a.lo*b.lo + c.lo ; d.hi = a.hi*(-b.hi) + c.hi    [no swap; negate b's hi term]
__device__ __forceinline__ f32x2 pk_fma_nh(f32x2 a, f32x2 b, f32x2 c) {
    f32x2 d;
    asm("v_pk_fma_f32 %0, %1, %2, %3 neg_hi:[0,1,0]"
        : "=v"(d) : "v"(a), "v"(b), "v"(c));
    return d;
}

// ---- cross-lane xor exchange within aligned 32-lane groups ----
// xor1/xor2: DPP quad_perm; xor8: DPP row_ror:8 (within 16-lane rows, ror8 == xor8).
// xor4/xor16: ds_swizzle BitMode (operates within 32-lane groups).
template<int XM>
__device__ __forceinline__ float sx(float v) {
    if constexpr (XM == 0) return v;
    const int x = __float_as_int(v);
    int r;
    if constexpr (XM == 1)      r = __builtin_amdgcn_update_dpp(0, x, 0xB1,  0xF, 0xF, true); // quad [1,0,3,2]
    else if constexpr (XM == 2) r = __builtin_amdgcn_update_dpp(0, x, 0x4E,  0xF, 0xF, true); // quad [2,3,0,1]
    else if constexpr (XM == 8) r = __builtin_amdgcn_update_dpp(0, x, 0x128, 0xF, 0xF, true); // row_ror:8
    else                        r = __builtin_amdgcn_ds_swizzle(x, (XM << 10) | 0x1F);        // 4, 16
    return __int_as_float(r);
}

// full (re,im) partner fetch: two 32-bit exchanges
template<int XM>
__device__ __forceinline__ f32x2 sxp(f32x2 v) {
    f32x2 r; r.x = sx<XM>(v.x); r.y = sx<XM>(v.y); return r;
}
// partner fetched with components SWAPPED: returns (partner.im, partner.re)
template<int XM>
__device__ __forceinline__ f32x2 sxp_swap(f32x2 v) {
    f32x2 r; r.x = sx<XM>(v.y); r.y = sx<XM>(v.x); return r;
}

__device__ __forceinline__ void swapv(f32x2& a, f32x2& b) { f32x2 t = a; a = b; b = t; }

// Layout: amp index g = i | (laneq<<3); qubit k -> bit k of g.
// Qubits 0..2 = local bits (i in [0,8)), qubits 3..7 = lane bits (laneq in [0,32)).

// ---- real 2x2 [[a,b],[d,e]] on qubit Q — packed: same real coef on re and im ----
template<int Q>
__device__ __forceinline__ void realGate(f32x2 (&v)[8], int laneq,
                                         float a, float b, float d, float e)
{
    if constexpr (Q < 3) {
        constexpr int M = 1 << Q;
        const f32x2 a2 = pkb(a), b2 = pkb(b), d2 = pkb(d), e2 = pkb(e);
#pragma unroll
        for (int i = 0; i < 8; i++) if (!(i & M)) {
            const int j = i | M;
            const f32x2 x0 = v[i], x1 = v[j];
            v[i] = pk_fma(a2, x0, pk_mul(b2, x1));
            v[j] = pk_fma(d2, x0, pk_mul(e2, x1));
        }
    } else {
        constexpr int XM = 1 << (Q - 3);
        const int bit = (laneq >> (Q - 3)) & 1;
        const f32x2 sc2 = pkb(bit ? e : a);   // self coefficient
        const f32x2 pc2 = pkb(bit ? d : b);   // partner coefficient
#pragma unroll
        for (int i = 0; i < 8; i++) {
            const f32x2 p = sxp<XM>(v[i]);
            v[i] = pk_fma(sc2, v[i], pk_mul(pc2, p));
        }
    }
}

// ---- RX: [[c, -i s], [-i s, c]] ----
// new.re = c*re + s*partner.im ; new.im = c*im - s*partner.re
template<int Q>
__device__ __forceinline__ void applyRX(f32x2 (&v)[8], int laneq, float c, float s)
{
    const f32x2 cc = pkb(c), ss = pkb(s);
    if constexpr (Q < 3) {
        constexpr int M = 1 << Q;
#pragma unroll
        for (int i = 0; i < 8; i++) if (!(i & M)) {
            const int j = i | M;
            const f32x2 x0 = v[i], x1 = v[j];
            // (c*x0r + s*x1i, c*x0i - s*x1r) via op_sel swap of the partner
            v[i] = pk_fma_sa_nh(x1, ss, pk_mul(cc, x0));
            v[j] = pk_fma_sa_nh(x0, ss, pk_mul(cc, x1));
        }
    } else {
        constexpr int XM = 1 << (Q - 3);
#pragma unroll
        for (int i = 0; i < 8; i++) {
            const f32x2 ps = sxp_swap<XM>(v[i]);   // (partner.im, partner.re)
            v[i] = pk_fma_nh(ps, ss, pk_mul(cc, v[i]));
        }
    }
}

// ---- RZ: diag(c - i s, c + i s) — shuffle-free, 2 pk ops per amp ----
template<int Q>
__device__ __forceinline__ void applyRZ(f32x2 (&v)[8], int laneq, float c, float s)
{
    const f32x2 cc = pkb(c);
    if constexpr (Q >= 3) {
        const int bit = (laneq >> (Q - 3)) & 1;
        const float t = bit ? -s : s;
        const f32x2 tt = pkb(t);
#pragma unroll
        for (int i = 0; i < 8; i++)
            v[i] = pk_fma_sa_nh(v[i], tt, pk_mul(cc, v[i]));   // (c*r + t*i, c*i - t*r)
    } else {
        const f32x2 ss = pkb(s);
#pragma unroll
        for (int i = 0; i < 8; i++) {
            if ((i >> Q) & 1) v[i] = pk_fma_sa_nl(v[i], ss, pk_mul(cc, v[i])); // t = -s
            else              v[i] = pk_fma_sa_nh(v[i], ss, pk_mul(cc, v[i])); // t = +s
        }
    }
}

// ---- Pauli Z ----
template<int Q>
__device__ __forceinline__ void applyZ(f32x2 (&v)[8], int laneq)
{
    if constexpr (Q >= 3) {
        const bool f = ((laneq >> (Q - 3)) & 1) != 0;
#pragma unroll
        for (int i = 0; i < 8; i++) {
            v[i].x = f ? -v[i].x : v[i].x;
            v[i].y = f ? -v[i].y : v[i].y;
        }
    } else {
#pragma unroll
        for (int i = 0; i < 8; i++) if ((i >> Q) & 1) {
            v[i].x = -v[i].x; v[i].y = -v[i].y;
        }
    }
}

// ---- Pauli X ----
template<int Q>
__device__ __forceinline__ void applyX(f32x2 (&v)[8], int laneq)
{
    if constexpr (Q < 3) {
        constexpr int M = 1 << Q;
#pragma unroll
        for (int i = 0; i < 8; i++) if (!(i & M)) {
            swapv(v[i], v[i | M]);
        }
    } else {
        constexpr int XM = 1 << (Q - 3);
#pragma unroll
        for (int i = 0; i < 8; i++) {
            v[i] = sxp<XM>(v[i]);
        }
    }
}

// ---- Pauli Y: [[0,-i],[i,0]] ----
template<int Q>
__device__ __forceinline__ void applyY(f32x2 (&v)[8], int laneq)
{
    if constexpr (Q < 3) {
        constexpr int M = 1 << Q;
#pragma unroll
        for (int i = 0; i < 8; i++) if (!(i & M)) {
            const int j = i | M;
            const f32x2 x0 = v[i], x1 = v[j];
            v[i] = pk2(x1.y, -x1.x);
            v[j] = pk2(-x0.y, x0.x);
        }
    } else {
        constexpr int XM = 1 << (Q - 3);
        const int bit = (laneq >> (Q - 3)) & 1;
#pragma unroll
        for (int i = 0; i < 8; i++) {
            const f32x2 p = sxp<XM>(v[i]);
            v[i].x = bit ? -p.y : p.y;
            v[i].y = bit ? p.x : -p.x;
        }
    }
}

// ---- CZ(C,T): sign flip when both bits set — shuffle-free ----
template<int C, int T>
__device__ __forceinline__ void applyCZ(f32x2 (&v)[8], int laneq)
{
#pragma unroll
    for (int i = 0; i < 8; i++) {
        const int g = i | (laneq << 3);
        const bool f = (((g >> C) & (g >> T)) & 1) != 0;
        v[i].x = f ? -v[i].x : v[i].x;
        v[i].y = f ? -v[i].y : v[i].y;
    }
}

// ---- controlled bit-flip: new[g] = old[g ^ M] when (g & CM) == CM ----
template<int CM, int M>
__device__ __forceinline__ void applyCPerm(f32x2 (&v)[8], int laneq)
{
    constexpr int LX  = M >> 3;    // target in lane bits -> exchange mask
    constexpr int PL  = M & 7;     // target in local bits
    constexpr int CML = CM & 7;    // controls in local bits
    constexpr int CMH = CM >> 3;   // controls in lane bits
    if constexpr (LX != 0) {
#pragma unroll
        for (int i = 0; i < 8; i++) {
            if ((i & CML) == CML) {
                const f32x2 p = sxp<LX>(v[i]);
                if constexpr (CMH != 0) {
                    const bool c = (laneq & CMH) == CMH;
                    v[i].x = c ? p.x : v[i].x;
                    v[i].y = c ? p.y : v[i].y;
                } else {
                    v[i] = p;
                }
            }
        }
    } else {
#pragma unroll
        for (int i = 0; i < 8; i++) {
            if (!(i & PL) && ((i & CML) == CML)) {
                const int j = i | PL;
                if constexpr (CMH != 0) {
                    const bool c = (laneq & CMH) == CMH;
                    const f32x2 t0 = v[i];
                    v[i].x = c ? v[j].x : v[i].x;  v[i].y = c ? v[j].y : v[i].y;
                    v[j].x = c ? t0.x : v[j].x;    v[j].y = c ? t0.y : v[j].y;
                } else {
                    swapv(v[i], v[j]);
                }
            }
        }
    }
}

// ---- CSWAP(C; T1,T2): swap bits T1,T2 when control set ----
template<int C, int T1, int T2>
__device__ __forceinline__ void applyCSWAP(f32x2 (&v)[8], int laneq)
{
    constexpr int M  = (1 << T1) | (1 << T2);
    constexpr int LX = M >> 3;
    constexpr int PL = M & 7;

    if constexpr (LX == 0) {
        // both targets local: representative i has T1-bit=1, T2-bit=0
#pragma unroll
        for (int i = 0; i < 8; i++) {
            if (((i >> T1) & 1) && !((i >> T2) & 1)) {
                bool skip = false;
                if constexpr (C < 3) { if (!((i >> C) & 1)) skip = true; }
                if (!skip) {
                    const int j = i ^ PL;
                    if constexpr (C >= 3) {
                        const bool c = ((laneq >> (C - 3)) & 1) != 0;
                        const f32x2 t0 = v[i];
                        v[i].x = c ? v[j].x : v[i].x;  v[i].y = c ? v[j].y : v[i].y;
                        v[j].x = c ? t0.x : v[j].x;    v[j].y = c ? t0.y : v[j].y;
                    } else {
                        swapv(v[i], v[j]);
                    }
                }
            }
        }
    } else if constexpr (PL == 0) {
        // both targets in lane bits
        bool c = ((((laneq >> (T1 - 3)) ^ (laneq >> (T2 - 3))) & 1) != 0);
        if constexpr (C >= 3) c = c && (((laneq >> (C - 3)) & 1) != 0);
#pragma unroll
        for (int i = 0; i < 8; i++) {
            bool skip = false;
            if constexpr (C < 3) { if (!((i >> C) & 1)) skip = true; }
            if (!skip) {
                const f32x2 p = sxp<LX>(v[i]);
                v[i].x = c ? p.x : v[i].x;
                v[i].y = c ? p.y : v[i].y;
            }
        }
    } else {
        // mixed: one local target (PL), one lane target (LX)
        constexpr int TL = (PL == (1 << T1)) ? T2 : T1;    // lane-resident target
        const bool laneT = ((laneq >> (TL - 3)) & 1) != 0;
        bool cc = true;
        if constexpr (C >= 3) cc = ((laneq >> (C - 3)) & 1) != 0;
#pragma unroll
        for (int i = 0; i < 8; i++) {
            if (!(i & PL)) {
                bool skip = false;
                if constexpr (C < 3) { if (!((i >> C) & 1)) skip = true; }
                if (!skip) {
                    const int j = i | PL;
                    // read partner-lane values before any write (lockstep)
                    const f32x2 a = sxp<LX>(v[j]);  // -> v[i]
                    const f32x2 b = sxp<LX>(v[i]);  // -> v[j]
                    const bool ci = cc && laneT;
                    const bool cj = cc && !laneT;
                    v[i].x = ci ? a.x : v[i].x;  v[i].y = ci ? a.y : v[i].y;
                    v[j].x = cj ? b.x : v[j].x;  v[j].y = cj ? b.y : v[j].y;
                }
            }
        }
    }
}

// ---- one node step; node N compile-time; design bits passed as packed scalars ----
// dryL: 4 bits (node&3), drotL: 8 bits (2 per node&3), dg2L: 16 bits (4 per node&3)
// All sincos values come from LDS (computed once in the prologue):
//   ryCS[n]  = (cos(feat_n/2), sin(feat_n/2))   per batch element (broadcast in group)
//   rotCS[k] = (cos(qp_k/2),  sin(qp_k/2))      block-uniform broadcast
template<int N>
__device__ __forceinline__ void nodeStep(f32x2 (&v)[8], int laneq,
                                         const float2* ryCS, const float2* rotCS,
                                         int layer, int dryL, int drotL, int dg2L)
{
    constexpr int N1 = (N + 1) & 7;
    constexpr int N2 = (N + 2) & 7;
    constexpr int SL = N & 3;

    const bool ryOn = ((dryL >> SL) & 1) != 0;
    const int rot = (drotL >> (2 * SL)) & 3;

    if (rot < 3) {
        const float2 t = rotCS[layer * NQ + N];     // ds_read_b64, uniform addr
        const float cb = t.x, sb = t.y;
        if (ryOn && rot == 1) {
            // RY(a) then RY(b) == RY(a+b): angle-sum on the cached pairs
            const float2 a = ryCS[N];
            const float c = cb * a.x - sb * a.y;
            const float s = sb * a.x + cb * a.y;
            realGate<N>(v, laneq, c, -s, s, c);
        } else {
            if (ryOn) {
                const float2 a = ryCS[N];
                realGate<N>(v, laneq, a.x, -a.y, a.y, a.x);
            }
            if (rot == 0)      applyRX<N>(v, laneq, cb, sb);
            else if (rot == 1) realGate<N>(v, laneq, cb, -sb, sb, cb);
            else               applyRZ<N>(v, laneq, cb, sb);
        }
    } else if (ryOn) {
        const float2 a = ryCS[N];
        realGate<N>(v, laneq, a.x, -a.y, a.y, a.x);
    }

    // 3) entangling / extra gate
    const int g2 = (dg2L >> (4 * SL)) & 15;
    switch (g2) {
        case 1: {
            const float r = 0.70710678118654752f;
            realGate<N>(v, laneq, r, r, r, -r);
        } break;
        case 2: applyX<N>(v, laneq); break;
        case 3: applyY<N>(v, laneq); break;
        case 4: applyZ<N>(v, laneq); break;
        case 5: applyCPerm<(1 << N), (1 << N1)>(v, laneq); break;
        case 6: applyCSWAP<N, N1, N2>(v, laneq); break;
        case 7: applyCPerm<(1 << N) | (1 << N1), (1 << N2)>(v, laneq); break;
        case 8: applyCZ<N, N1>(v, laneq); break;
        default: break;
    }
}

__global__ __launch_bounds__(256, 4) void qsim_kernel(
    const float* __restrict__ feats,    // [B, 8]
    const float* __restrict__ qp,       // [48]
    const int* __restrict__ dry,        // [24]
    const int* __restrict__ drot,       // [24]
    const int* __restrict__ dg2,        // [24]
    float* __restrict__ out,            // [B, 8]
    int B)
{
    __shared__ float2 lds_ry[8][8];     // per-group (c,s) of RY angles, 512 B
    __shared__ float2 lds_rot[48];      // block-uniform (c,s) of trainable angles, 384 B

    const int tid   = threadIdx.x;
    const int laneq = tid & 31;                               // lane within element group
    const int grp   = tid >> 5;                               // group within block (0..7)
    const int b     = blockIdx.x * 8 + grp;                   // batch element

    // ---- prologue: sincos caches (each value computed exactly once per block) ----
    if (tid < 48) {
        const float th = qp[tid] * HALF_INV2PI;               // revolutions of theta/2
        lds_rot[tid] = make_float2(__builtin_amdgcn_cosf(th), __builtin_amdgcn_sinf(th));
    }
    if (laneq < 8) {
        const float th = feats[(size_t)b * NQ + laneq] * HALF_INV2PI;
        lds_ry[grp][laneq] = make_float2(__builtin_amdgcn_cosf(th), __builtin_amdgcn_sinf(th));
    }

    // ---- pack the (uniform) design into SGPRs via readfirstlane (dwordx4 loads) ----
    uint32_t dryP = 0;
    uint64_t drotP = 0;
    uint32_t g2P0 = 0, g2P1 = 0, g2P2 = 0;
#pragma unroll
    for (int q = 0; q < 6; q++) {
        const int4 a = ((const int4*)dry)[q];
        dryP |= (uint32_t)(__builtin_amdgcn_readfirstlane(a.x) & 1) << (4 * q + 0);
        dryP |= (uint32_t)(__builtin_amdgcn_readfirstlane(a.y) & 1) << (4 * q + 1);
        dryP |= (uint32_t)(__builtin_amdgcn_readfirstlane(a.z) & 1) << (4 * q + 2);
        dryP |= (uint32_t)(__builtin_amdgcn_readfirstlane(a.w) & 1) << (4 * q + 3);
        const int4 r = ((const int4*)drot)[q];
        drotP |= (uint64_t)(__builtin_amdgcn_readfirstlane(r.x) & 3) << (8 * q + 0);
        drotP |= (uint64_t)(__builtin_amdgcn_readfirstlane(r.y) & 3) << (8 * q + 2);
        drotP |= (uint64_t)(__builtin_amdgcn_readfirstlane(r.z) & 3) << (8 * q + 4);
        drotP |= (uint64_t)(__builtin_amdgcn_readfirstlane(r.w) & 3) << (8 * q + 6);
        const int4 g = ((const int4*)dg2)[q];
        const uint32_t gg = ((uint32_t)(__builtin_amdgcn_readfirstlane(g.x) & 15))
                          | ((uint32_t)(__builtin_amdgcn_readfirstlane(g.y) & 15) << 4)
                          | ((uint32_t)(__builtin_amdgcn_readfirstlane(g.z) & 15) << 8)
                          | ((uint32_t)(__builtin_amdgcn_readfirstlane(g.w) & 15) << 12);
        if      (q == 0) g2P0 |= gg;
        else if (q == 1) g2P0 |= gg << 16;
        else if (q == 2) g2P1 |= gg;
        else if (q == 3) g2P1 |= gg << 16;
        else if (q == 4) g2P2 |= gg;
        else             g2P2 |= gg << 16;
    }

    __syncthreads();                    // lds_rot written by wave 0, read by all waves

    const float2* ryCS  = &lds_ry[grp][0];
    const float2* rotCS = &lds_rot[0];

    // H^8 |0> = uniform amplitude 1/16
    f32x2 v[8];
#pragma unroll
    for (int i = 0; i < 8; i++) { v[i] = pk2(0.0625f, 0.0f); }

#pragma unroll 1
    for (int layer = 0; layer < 6; layer++) {
        // per-layer design slice (scalar shifts, no memory)
        const int dryL  = (int)((dryP >> (layer * 4)) & 0xF);
        const int drotL = (int)((drotP >> (layer * 8)) & 0xFF);
        const uint32_t g2w = (layer >= 4) ? g2P2 : ((layer >= 2) ? g2P1 : g2P0);
        const int dg2L  = (int)((g2w >> ((layer & 1) * 16)) & 0xFFFF);

        nodeStep<0>(v, laneq, ryCS, rotCS, layer, dryL, drotL, dg2L);
        nodeStep<1>(v, laneq, ryCS, rotCS, layer, dryL, drotL, dg2L);
        nodeStep<2>(v, laneq, ryCS, rotCS, layer, dryL, drotL, dg2L);
        nodeStep<3>(v, laneq, ryCS, rotCS, layer, dryL, drotL, dg2L);
        nodeStep<4>(v, laneq, ryCS, rotCS, layer, dryL, drotL, dg2L);
        nodeStep<5>(v, laneq, ryCS, rotCS, layer, dryL, drotL, dg2L);
        nodeStep<6>(v, laneq, ryCS, rotCS, layer, dryL, drotL, dg2L);
        nodeStep<7>(v, laneq, ryCS, rotCS, layer, dryL, drotL, dg2L);
    }

    // ---- epilogue: <Z_q> ----
    float tot = 0.f, s0 = 0.f, s1 = 0.f, s2 = 0.f;
#pragma unroll
    for (int i = 0; i < 8; i++) {
        const float p = v[i].x * v[i].x + v[i].y * v[i].y;
        tot += p;
        if (!(i & 1)) s0 += p;
        if (!(i & 2)) s1 += p;
        if (!(i & 4)) s2 += p;
    }
    float e[3] = { 2.f * s0 - tot, 2.f * s1 - tot, 2.f * s2 - tot };

    // sum e[0..2] over the 32-lane group
#pragma unroll
    for (int q = 0; q < 3; q++) {
        e[q] += sx<1>(e[q]);
        e[q] += sx<2>(e[q]);
        e[q] += sx<4>(e[q]);
        e[q] += sx<8>(e[q]);
        e[q] += sx<16>(e[q]);
    }
    // FWHT on tot: after 5 stages, laneq = (1<<k) holds <Z_{3+k}>
    { float pv = sx<1>(tot);  tot = (laneq & 1)  ? (pv - tot) : (pv + tot); }
    { float pv = sx<2>(tot);  tot = (laneq & 2)  ? (pv - tot) : (pv + tot); }
    { float pv = sx<4>(tot);  tot = (laneq & 4)  ? (pv - tot) : (pv + tot); }
    { float pv = sx<8>(tot);  tot = (laneq & 8)  ? (pv - tot) : (pv + tot); }
    { float pv = sx<16>(tot); tot = (laneq & 16) ? (pv - tot) : (pv + tot); }

    float* ob = out + (size_t)b * NQ;
    if (laneq == 0) { ob[0] = e[0]; ob[1] = e[1]; ob[2] = e[2]; }
    if (laneq && !(laneq & (laneq - 1)))          // laneq in {1,2,4,8,16}
        ob[3 + __builtin_ctz(laneq)] = tot;
}

extern "C" void kernel_launch(void* const* d_in, const int* in_sizes, int n_in,
                              void* d_out, int out_size, void* d_ws, size_t ws_size,
                              hipStream_t stream)
{
    (void)n_in; (void)out_size; (void)d_ws; (void)ws_size;
    const float* feats   = (const float*)d_in[0];
    const float* qparams = (const float*)d_in[1];
    const int* dry       = (const int*)d_in[2];
    const int* drot      = (const int*)d_in[3];
    const int* dg2       = (const int*)d_in[4];
    float* out           = (float*)d_out;

    const int B = in_sizes[0] / NQ;             // 16384
    const int blocks = (B + 7) / 8;             // 8 elements per 256-thread block
    qsim_kernel<<<blocks, 256, 0, stream>>>(feats, qparams, dry, drot, dg2, out, B);
}